// Round 9
// baseline (246.475 us; speedup 1.0000x reference)
//
#include <hip/hip_runtime.h>

// B=4, S=512, HID=1024, H=16, D=64, NREL=64
// ws: qb bf16(B,H,S,D) | kb bf16(B,H,S,D) | vt bf16(B,H,D,S) | attn_b bf16(B*S,HID)
//     Xq,Xk,Xv bf16 | Wqb,Wkb,Wvb,Wob bf16

typedef __attribute__((ext_vector_type(8))) short bf16x8 __attribute__((may_alias));
typedef __attribute__((ext_vector_type(4))) float f32x4;

__device__ __forceinline__ short f2bf(float x) {
    unsigned u = __float_as_uint(x);
    u += 0x7fff + ((u >> 16) & 1);          // RNE; finite inputs
    return (short)(u >> 16);
}

__device__ __forceinline__ void async16(void* lds, const void* g) {
    __builtin_amdgcn_global_load_lds(
        (const __attribute__((address_space(1))) void*)g,
        (__attribute__((address_space(3))) void*)lds, 16, 0, 0);
}

// ---------- fused fp32 -> bf16 cast of 3 X (2M ea) + 4 W (1M ea) ----------
__global__ __launch_bounds__(256)
void cast_all(const float* __restrict__ x0, const float* __restrict__ x1, const float* __restrict__ x2,
              const float* __restrict__ w0, const float* __restrict__ w1,
              const float* __restrict__ w2, const float* __restrict__ w3,
              short* __restrict__ y0, short* __restrict__ y1, short* __restrict__ y2,
              short* __restrict__ u0, short* __restrict__ u1,
              short* __restrict__ u2, short* __restrict__ u3)
{
    size_t i = (size_t)blockIdx.x * 256 + threadIdx.x;
    const float* src; short* dst; size_t off;
    if (i < 3u*524288u) {
        int s = (int)(i / 524288u); off = i % 524288u;
        src = s == 0 ? x0 : (s == 1 ? x1 : x2);
        dst = s == 0 ? y0 : (s == 1 ? y1 : y2);
    } else {
        size_t j = i - 3u*524288u;
        int s = (int)(j / 262144u); off = j % 262144u;
        src = s == 0 ? w0 : (s == 1 ? w1 : (s == 2 ? w2 : w3));
        dst = s == 0 ? u0 : (s == 1 ? u1 : (s == 2 ? u2 : u3));
    }
    float4 f = ((const float4*)src)[off];
    short4 o; o.x = f2bf(f.x); o.y = f2bf(f.y); o.z = f2bf(f.z); o.w = f2bf(f.w);
    ((short4*)dst)[off] = o;
}

// ---------- bf16 MFMA GEMM, tile 128(M)x64(N), BK=64, dbuf: O = A @ B^T + bias ----------
// 4 waves in 2x2; wave does 64(M)x32(N) = 4x2 MFMA tiles.
// mode 0: O fp32 flat (M,1024). mode 1: O bf16; z<2 -> (b,h,s,d); z==2 -> (b,h,d,s).
__global__ __launch_bounds__(256)
void gemm12864(const short* __restrict__ A0, const short* __restrict__ A1, const short* __restrict__ A2,
               const short* __restrict__ B0, const short* __restrict__ B1, const short* __restrict__ B2,
               const float* __restrict__ c0, const float* __restrict__ c1, const float* __restrict__ c2,
               void* __restrict__ O0, void* __restrict__ O1, void* __restrict__ O2,
               int mode)
{
    __shared__ short ldsw[2 * 12288];   // [buf][A 128*64 | B 64*64]; epilogue reuses as Tls

    const int z = blockIdx.z;
    const short* A    = z == 0 ? A0 : (z == 1 ? A1 : A2);
    const short* Bm   = z == 0 ? B0 : (z == 1 ? B1 : B2);
    const float* bias = z == 0 ? c0 : (z == 1 ? c1 : c2);
    void*        O    = z == 0 ? O0 : (z == 1 ? O1 : O2);

    const int t = threadIdx.x;
    const int lane = t & 63, w = t >> 6;
    const int wr = w >> 1, wc = w & 1;
    const int quad = lane >> 4, cl = lane & 15;
    const int rowBase = blockIdx.y * 128;
    const int colBase = blockIdx.x * 64;
    const int gl = ((lane & 7) - (lane >> 3)) & 7;

    f32x4 acc[4][2];
#pragma unroll
    for (int i = 0; i < 4; ++i)
#pragma unroll
        for (int j = 0; j < 2; ++j) acc[i][j] = (f32x4){0.f, 0.f, 0.f, 0.f};

    const int rstage = w * 8 + (lane >> 3);
    const short* Ag = A  + (size_t)(rowBase + rstage) * 1024 + gl * 8;
    const short* Bg = Bm + (size_t)(colBase + rstage) * 1024 + gl * 8;

    {
        short* Als = ldsw;
        short* Bls = ldsw + 8192;
#pragma unroll
        for (int i = 0; i < 4; ++i)
            async16(&Als[(i * 32 + w * 8) * 64], Ag + (size_t)i * 32 * 1024);
#pragma unroll
        for (int i = 0; i < 2; ++i)
            async16(&Bls[(i * 32 + w * 8) * 64], Bg + (size_t)i * 32 * 1024);
    }

    for (int it = 0; it < 16; ++it) {
        const int cur = it & 1;
        __syncthreads();
        if (it < 15) {
            short* Als = ldsw + (cur ^ 1) * 12288;
            short* Bls = Als + 8192;
            const int k0 = (it + 1) * 64;
#pragma unroll
            for (int i = 0; i < 4; ++i)
                async16(&Als[(i * 32 + w * 8) * 64], Ag + (size_t)i * 32 * 1024 + k0);
#pragma unroll
            for (int i = 0; i < 2; ++i)
                async16(&Bls[(i * 32 + w * 8) * 64], Bg + (size_t)i * 32 * 1024 + k0);
        }
        const short* Als = ldsw + cur * 12288;
        const short* Bls = Als + 8192;
#pragma unroll
        for (int kk = 0; kk < 2; ++kk) {
            bf16x8 a[4], b[2];
#pragma unroll
            for (int mi = 0; mi < 4; ++mi) {
                int r = wr * 64 + mi * 16 + cl;
                int s = (kk * 4 + quad + r) & 7;
                a[mi] = *(const bf16x8*)&Als[r * 64 + s * 8];
            }
#pragma unroll
            for (int ni = 0; ni < 2; ++ni) {
                int r = wc * 32 + ni * 16 + cl;
                int s = (kk * 4 + quad + r) & 7;
                b[ni] = *(const bf16x8*)&Bls[r * 64 + s * 8];
            }
#pragma unroll
            for (int mi = 0; mi < 4; ++mi)
#pragma unroll
                for (int ni = 0; ni < 2; ++ni)
                    acc[mi][ni] = __builtin_amdgcn_mfma_f32_16x16x32_bf16(
                        a[mi], b[ni], acc[mi][ni], 0, 0, 0);
        }
    }

    if (mode == 0) {
#pragma unroll
        for (int mi = 0; mi < 4; ++mi)
#pragma unroll
            for (int ni = 0; ni < 2; ++ni) {
                int col = colBase + wc * 32 + ni * 16 + cl;
                float bv = bias[col];
#pragma unroll
                for (int reg = 0; reg < 4; ++reg) {
                    int row = rowBase + wr * 64 + mi * 16 + quad * 4 + reg;
                    ((float*)O)[(size_t)row * 1024 + col] = acc[mi][ni][reg] + bv;
                }
            }
        return;
    }

    __syncthreads();
    short* Tls = ldsw;
    if (z == 2) {
        // vt (b,h,d,s): Tls[64][136]
#pragma unroll
        for (int mi = 0; mi < 4; ++mi)
#pragma unroll
            for (int ni = 0; ni < 2; ++ni) {
                int d = wc * 32 + ni * 16 + cl;
                float bv = bias[colBase + d];
                short4 pk;
                pk.x = f2bf(acc[mi][ni][0] + bv);
                pk.y = f2bf(acc[mi][ni][1] + bv);
                pk.z = f2bf(acc[mi][ni][2] + bv);
                pk.w = f2bf(acc[mi][ni][3] + bv);
                int sl = wr * 64 + mi * 16 + quad * 4;
                *(short4*)&Tls[d * 136 + sl] = pk;
            }
        __syncthreads();
        int d = t >> 2, s0 = (t & 3) * 32;
        int bb = rowBase >> 9, sBase = rowBase & 511, hh = colBase >> 6;
        short* dst = (short*)O + (((size_t)(bb * 16 + hh) * 64 + d) << 9) + sBase + s0;
#pragma unroll
        for (int j = 0; j < 4; ++j)
            *(bf16x8*)(dst + j * 8) = *(const bf16x8*)&Tls[d * 136 + s0 + j * 8];
    } else {
        // bhsd: Tls[128][72]
#pragma unroll
        for (int mi = 0; mi < 4; ++mi)
#pragma unroll
            for (int ni = 0; ni < 2; ++ni) {
                int d = wc * 32 + ni * 16 + cl;
                float bv = bias[colBase + d];
#pragma unroll
                for (int reg = 0; reg < 4; ++reg) {
                    int sl = wr * 64 + mi * 16 + quad * 4 + reg;
                    Tls[sl * 72 + d] = f2bf(acc[mi][ni][reg] + bv);
                }
            }
        __syncthreads();
        int sl = t >> 1, half = t & 1;
        int bb = rowBase >> 9, sBase = rowBase & 511, hh = colBase >> 6;
        short* dst = (short*)O + (((size_t)(bb * 16 + hh) * 512 + sBase + sl) << 6) + half * 32;
#pragma unroll
        for (int j = 0; j < 4; ++j)
            *(bf16x8*)(dst + j * 8) = *(const bf16x8*)&Tls[sl * 72 + half * 32 + j * 8];
    }
}

// ---------------- Attention: 2-wave blocks, key-split, wave-private state ----------------
// block = 128 thr = (b,h, 16-query tile); wave w owns keys [w*256,(w+1)*256).
// LDS (bytes):
//   0      qwr   f32[16][68] shared (4352)       [wave w writes r-tiles 2w,2w+1]
//   4352   bins  2 x f32[16][68] wave-private (8704)
//   13056  Pst   2 x short[16][72] wave-private (4608)
//   17664  Opart 2 x f32[16][68] (8704)
//   26368  Lacc  f32[32] (128)
#define AT_BINS  4352
#define AT_PST   13056
#define AT_OPART 17664
#define AT_LACC  26368
#define AT_TOT   26496

__global__ __launch_bounds__(128)
void attn_kernel(const short* __restrict__ qg, const short* __restrict__ kg,
                 const short* __restrict__ vtg, const int* __restrict__ mask,
                 const float* __restrict__ relk, const float* __restrict__ relv,
                 short* __restrict__ attn_b)
{
    __shared__ __align__(16) char pool[AT_TOT];
    float* qwr  = (float*)pool;
    float* Lacc = (float*)(pool + AT_LACC);

    const int t = threadIdx.x, lane = t & 63, w = t >> 6;
    const int quad = lane >> 4, cl = lane & 15;
    const int bid = blockIdx.x;
    const int bh = bid & 63, qbk = bid >> 6;   // XCD-friendly: bh%8 fixes XCD
    const int b = bh >> 4, h = bh & 15, q0 = qbk * 16;

    const short* qbase = qg  + ((size_t)bh * 512 + q0) * 64;
    const short* kbase = kg  + (size_t)bh * 512 * 64;
    const short* vbase = vtg + (size_t)bh * 64 * 512;
    const int*   mb    = mask + (size_t)b * 512 * 512 + (size_t)q0 * 512;

    float* bins  = (float*)(pool + AT_BINS  + w * 4352);
    short* Pst   = (short*)(pool + AT_PST   + w * 2304);
    float* Opart = (float*)(pool + AT_OPART + w * 4352);

    // zero wave-private bins
    for (int i = lane; i < 16 * 68; i += 64) bins[i] = 0.f;

    // Q A-fragments direct from global
    bf16x8 qa0 = *(const bf16x8*)(qbase + cl * 64 + quad * 8);
    bf16x8 qa1 = *(const bf16x8*)(qbase + cl * 64 + 32 + quad * 8);

    // qrel: wave w computes r-tiles 2w, 2w+1
#pragma unroll
    for (int rt2 = 0; rt2 < 2; ++rt2) {
        const int rt = w * 2 + rt2;
        const float* kp = relk + (size_t)(rt * 16 + cl) * 64 + quad * 8;
        bf16x8 rb0, rb1;
#pragma unroll
        for (int j = 0; j < 8; ++j) rb0[j] = f2bf(kp[j]);
#pragma unroll
        for (int j = 0; j < 8; ++j) rb1[j] = f2bf(kp[32 + j]);
        f32x4 qr = (f32x4){0.f, 0.f, 0.f, 0.f};
        qr = __builtin_amdgcn_mfma_f32_16x16x32_bf16(qa0, rb0, qr, 0, 0, 0);
        qr = __builtin_amdgcn_mfma_f32_16x16x32_bf16(qa1, rb1, qr, 0, 0, 0);
#pragma unroll
        for (int reg = 0; reg < 4; ++reg)
            qwr[(quad * 4 + reg) * 68 + rt * 16 + cl] = qr[reg];
    }
    __syncthreads();   // #0: qwr complete

    // ---- K-loop: 4 chunks of 64 keys; all chunk loads batched up-front ----
    f32x4 oacc[4];
#pragma unroll
    for (int dt = 0; dt < 4; ++dt) oacc[dt] = (f32x4){0.f, 0.f, 0.f, 0.f};
    float lpart[4] = {0.f, 0.f, 0.f, 0.f};

    for (int c = 0; c < 4; ++c) {
        const int k0 = w * 256 + c * 64;
        // batched loads: K fragments, V fragments, mask ids -> registers first
        bf16x8 kb[8], vb[8];
        int idv[16];
#pragma unroll
        for (int nt = 0; nt < 4; ++nt) {
            const short* kp = kbase + (size_t)(k0 + nt * 16 + cl) * 64 + quad * 8;
            kb[nt * 2]     = *(const bf16x8*)kp;
            kb[nt * 2 + 1] = *(const bf16x8*)(kp + 32);
        }
#pragma unroll
        for (int dt = 0; dt < 4; ++dt) {
            const short* vp = vbase + (size_t)(dt * 16 + cl) * 512 + k0 + quad * 8;
            vb[dt * 2]     = *(const bf16x8*)vp;
            vb[dt * 2 + 1] = *(const bf16x8*)(vp + 32);
        }
#pragma unroll
        for (int nt = 0; nt < 4; ++nt)
#pragma unroll
            for (int reg = 0; reg < 4; ++reg)
                idv[nt * 4 + reg] = mb[(quad * 4 + reg) * 512 + k0 + nt * 16 + cl];

#pragma unroll
        for (int nt = 0; nt < 4; ++nt) {
            f32x4 s = (f32x4){0.f, 0.f, 0.f, 0.f};
            s = __builtin_amdgcn_mfma_f32_16x16x32_bf16(qa0, kb[nt * 2],     s, 0, 0, 0);
            s = __builtin_amdgcn_mfma_f32_16x16x32_bf16(qa1, kb[nt * 2 + 1], s, 0, 0, 0);
#pragma unroll
            for (int reg = 0; reg < 4; ++reg) {
                int q = quad * 4 + reg;
                int id = idv[nt * 4 + reg];
                float sc = (s[reg] + 0.25f * qwr[q * 68 + id]) * 0.125f;
                float p = (id == 0) ? 0.f : __expf(sc);   // no-max softmax; masked -> 0
                lpart[reg] += p;
                atomicAdd(&bins[q * 68 + id], p);
                Pst[q * 72 + nt * 16 + cl] = f2bf(p);
            }
        }
        // P C-layout -> A-layout via wave-private LDS (in-wave RAW)
        bf16x8 pa0 = *(const bf16x8*)&Pst[cl * 72 + quad * 8];
        bf16x8 pa1 = *(const bf16x8*)&Pst[cl * 72 + 32 + quad * 8];
#pragma unroll
        for (int dt = 0; dt < 4; ++dt) {
            oacc[dt] = __builtin_amdgcn_mfma_f32_16x16x32_bf16(pa0, vb[dt * 2],     oacc[dt], 0, 0, 0);
            oacc[dt] = __builtin_amdgcn_mfma_f32_16x16x32_bf16(pa1, vb[dt * 2 + 1], oacc[dt], 0, 0, 0);
        }
    }

    // publish per-wave partials
#pragma unroll
    for (int reg = 0; reg < 4; ++reg) {
        int q = quad * 4 + reg;
#pragma unroll
        for (int dt = 0; dt < 4; ++dt)
            Opart[q * 68 + dt * 16 + cl] = oacc[dt][reg];
        float lsum = lpart[reg];
#pragma unroll
        for (int m = 8; m >= 1; m >>= 1) lsum += __shfl_xor(lsum, m);
        if (cl == 0) Lacc[w * 16 + q] = lsum;
    }
    __syncthreads();   // #1: qwr dead; Opart, Lacc, both bins complete

    // merged bins -> A-fragment in-register
    const float* b0 = (const float*)(pool + AT_BINS);
    const float* b1 = (const float*)(pool + AT_BINS + 4352);
    bf16x8 ba0, ba1;
#pragma unroll
    for (int j = 0; j < 8; ++j)
        ba0[j] = f2bf(b0[cl * 68 + quad * 8 + j] + b1[cl * 68 + quad * 8 + j]);
#pragma unroll
    for (int j = 0; j < 8; ++j)
        ba1[j] = f2bf(b0[cl * 68 + 32 + quad * 8 + j] + b1[cl * 68 + 32 + quad * 8 + j]);

    float invq[4];
#pragma unroll
    for (int reg = 0; reg < 4; ++reg) {
        int q = quad * 4 + reg;
        invq[reg] = 1.0f / (Lacc[q] + Lacc[16 + q]);
    }

    const float* Op0 = (const float*)(pool + AT_OPART);
    const float* Op1 = (const float*)(pool + AT_OPART + 4352);

    // rel_out + combine + store: wave w handles d-tiles 2w, 2w+1
#pragma unroll
    for (int dt2 = 0; dt2 < 2; ++dt2) {
        const int dt = w * 2 + dt2;
        const float* rp = relv + (size_t)(quad * 8) * 64 + dt * 16 + cl;
        bf16x8 rv0, rv1;
#pragma unroll
        for (int j = 0; j < 8; ++j) rv0[j] = f2bf(rp[j * 64]);
#pragma unroll
        for (int j = 0; j < 8; ++j) rv1[j] = f2bf(rp[2048 + j * 64]);
        f32x4 racc = (f32x4){0.f, 0.f, 0.f, 0.f};
        racc = __builtin_amdgcn_mfma_f32_16x16x32_bf16(ba0, rv0, racc, 0, 0, 0);
        racc = __builtin_amdgcn_mfma_f32_16x16x32_bf16(ba1, rv1, racc, 0, 0, 0);
#pragma unroll
        for (int reg = 0; reg < 4; ++reg) {
            int q = quad * 4 + reg;
            int d = dt * 16 + cl;
            float val = (Op0[q * 68 + d] + Op1[q * 68 + d] + 0.25f * racc[reg]) * invq[reg];
            attn_b[(size_t)(b * 512 + q0 + q) * 1024 + h * 64 + d] = f2bf(val);
        }
    }
}

extern "C" void kernel_launch(void* const* d_in, const int* in_sizes, int n_in,
                              void* d_out, int out_size, void* d_ws, size_t ws_size,
                              hipStream_t stream)
{
    const float* q_in = (const float*)d_in[0];
    const float* k_in = (const float*)d_in[1];
    const float* v_in = (const float*)d_in[2];
    const int*   mask = (const int*)d_in[3];
    const float* Wq   = (const float*)d_in[4];
    const float* bq   = (const float*)d_in[5];
    const float* Wk   = (const float*)d_in[6];
    const float* bk   = (const float*)d_in[7];
    const float* Wv   = (const float*)d_in[8];
    const float* bv   = (const float*)d_in[9];
    const float* Wo   = (const float*)d_in[10];
    const float* bo   = (const float*)d_in[11];
    const float* relk = (const float*)d_in[12];
    const float* relv = (const float*)d_in[13];

    char* ws = (char*)d_ws;
    short* qb     = (short*)(ws);                  // 4MB
    short* kb     = (short*)(ws + (4u  << 20));    // 4MB
    short* vt     = (short*)(ws + (8u  << 20));    // 4MB
    short* attn_b = (short*)(ws + (12u << 20));    // 4MB
    short* Xq     = (short*)(ws + (16u << 20));    // 4MB
    short* Xk     = (short*)(ws + (20u << 20));
    short* Xv     = (short*)(ws + (24u << 20));
    short* Wqb    = (short*)(ws + (28u << 20));    // 2MB
    short* Wkb    = (short*)(ws + (30u << 20));
    short* Wvb    = (short*)(ws + (32u << 20));
    short* Wob    = (short*)(ws + (34u << 20));

    cast_all<<<10240, 256, 0, stream>>>(q_in, k_in, v_in, Wq, Wk, Wv, Wo,
                                        Xq, Xk, Xv, Wqb, Wkb, Wvb, Wob);

    gemm12864<<<dim3(16, 16, 3), 256, 0, stream>>>(
        Xq, Xk, Xv, Wqb, Wkb, Wvb, bq, bk, bv, qb, kb, vt, 1);

    attn_kernel<<<dim3(2048), 128, 0, stream>>>(qb, kb, vt, mask, relk, relv, attn_b);

    gemm12864<<<dim3(16, 16, 1), 256, 0, stream>>>(
        attn_b, attn_b, attn_b, Wob, Wob, Wob, bo, bo, bo,
        (void*)d_out, (void*)d_out, (void*)d_out, 0);
}

// Round 10
// 244.306 us; speedup vs baseline: 1.0089x; 1.0089x over previous
//
#include <hip/hip_runtime.h>

// B=4, S=512, HID=1024, H=16, D=64, NREL=64
// ws: qb bf16(B,H,S,D) | kb bf16(B,H,S,D) | vt bf16(B,H,D,S) | attn_b bf16(B*S,HID)
//     Xq,Xk,Xv bf16 | Wqb,Wkb,Wvb,Wob bf16

typedef __attribute__((ext_vector_type(8))) short bf16x8 __attribute__((may_alias));
typedef __attribute__((ext_vector_type(4))) float f32x4;

__device__ __forceinline__ short f2bf(float x) {
    unsigned u = __float_as_uint(x);
    u += 0x7fff + ((u >> 16) & 1);          // RNE; finite inputs
    return (short)(u >> 16);
}

__device__ __forceinline__ void async16(void* lds, const void* g) {
    __builtin_amdgcn_global_load_lds(
        (const __attribute__((address_space(1))) void*)g,
        (__attribute__((address_space(3))) void*)lds, 16, 0, 0);
}

// ---------- fused fp32 -> bf16 cast of 3 X (2M ea) + 4 W (1M ea) ----------
__global__ __launch_bounds__(256)
void cast_all(const float* __restrict__ x0, const float* __restrict__ x1, const float* __restrict__ x2,
              const float* __restrict__ w0, const float* __restrict__ w1,
              const float* __restrict__ w2, const float* __restrict__ w3,
              short* __restrict__ y0, short* __restrict__ y1, short* __restrict__ y2,
              short* __restrict__ u0, short* __restrict__ u1,
              short* __restrict__ u2, short* __restrict__ u3)
{
    size_t i = (size_t)blockIdx.x * 256 + threadIdx.x;
    const float* src; short* dst; size_t off;
    if (i < 3u*524288u) {
        int s = (int)(i / 524288u); off = i % 524288u;
        src = s == 0 ? x0 : (s == 1 ? x1 : x2);
        dst = s == 0 ? y0 : (s == 1 ? y1 : y2);
    } else {
        size_t j = i - 3u*524288u;
        int s = (int)(j / 262144u); off = j % 262144u;
        src = s == 0 ? w0 : (s == 1 ? w1 : (s == 2 ? w2 : w3));
        dst = s == 0 ? u0 : (s == 1 ? u1 : (s == 2 ? u2 : u3));
    }
    float4 f = ((const float4*)src)[off];
    short4 o; o.x = f2bf(f.x); o.y = f2bf(f.y); o.z = f2bf(f.z); o.w = f2bf(f.w);
    ((short4*)dst)[off] = o;
}

// ---------- bf16 MFMA GEMM, tile 128(M)x64(N), BK=64, dbuf: O = A @ B^T + bias ----------
__global__ __launch_bounds__(256)
void gemm12864(const short* __restrict__ A0, const short* __restrict__ A1, const short* __restrict__ A2,
               const short* __restrict__ B0, const short* __restrict__ B1, const short* __restrict__ B2,
               const float* __restrict__ c0, const float* __restrict__ c1, const float* __restrict__ c2,
               void* __restrict__ O0, void* __restrict__ O1, void* __restrict__ O2,
               int mode)
{
    __shared__ short ldsw[2 * 12288];   // [buf][A 128*64 | B 64*64]; epilogue reuses as Tls

    const int z = blockIdx.z;
    const short* A    = z == 0 ? A0 : (z == 1 ? A1 : A2);
    const short* Bm   = z == 0 ? B0 : (z == 1 ? B1 : B2);
    const float* bias = z == 0 ? c0 : (z == 1 ? c1 : c2);
    void*        O    = z == 0 ? O0 : (z == 1 ? O1 : O2);

    const int t = threadIdx.x;
    const int lane = t & 63, w = t >> 6;
    const int wr = w >> 1, wc = w & 1;
    const int quad = lane >> 4, cl = lane & 15;
    const int rowBase = blockIdx.y * 128;
    const int colBase = blockIdx.x * 64;
    const int gl = ((lane & 7) - (lane >> 3)) & 7;

    f32x4 acc[4][2];
#pragma unroll
    for (int i = 0; i < 4; ++i)
#pragma unroll
        for (int j = 0; j < 2; ++j) acc[i][j] = (f32x4){0.f, 0.f, 0.f, 0.f};

    const int rstage = w * 8 + (lane >> 3);
    const short* Ag = A  + (size_t)(rowBase + rstage) * 1024 + gl * 8;
    const short* Bg = Bm + (size_t)(colBase + rstage) * 1024 + gl * 8;

    {
        short* Als = ldsw;
        short* Bls = ldsw + 8192;
#pragma unroll
        for (int i = 0; i < 4; ++i)
            async16(&Als[(i * 32 + w * 8) * 64], Ag + (size_t)i * 32 * 1024);
#pragma unroll
        for (int i = 0; i < 2; ++i)
            async16(&Bls[(i * 32 + w * 8) * 64], Bg + (size_t)i * 32 * 1024);
    }

    for (int it = 0; it < 16; ++it) {
        const int cur = it & 1;
        __syncthreads();
        if (it < 15) {
            short* Als = ldsw + (cur ^ 1) * 12288;
            short* Bls = Als + 8192;
            const int k0 = (it + 1) * 64;
#pragma unroll
            for (int i = 0; i < 4; ++i)
                async16(&Als[(i * 32 + w * 8) * 64], Ag + (size_t)i * 32 * 1024 + k0);
#pragma unroll
            for (int i = 0; i < 2; ++i)
                async16(&Bls[(i * 32 + w * 8) * 64], Bg + (size_t)i * 32 * 1024 + k0);
        }
        const short* Als = ldsw + cur * 12288;
        const short* Bls = Als + 8192;
#pragma unroll
        for (int kk = 0; kk < 2; ++kk) {
            bf16x8 a[4], b[2];
#pragma unroll
            for (int mi = 0; mi < 4; ++mi) {
                int r = wr * 64 + mi * 16 + cl;
                int s = (kk * 4 + quad + r) & 7;
                a[mi] = *(const bf16x8*)&Als[r * 64 + s * 8];
            }
#pragma unroll
            for (int ni = 0; ni < 2; ++ni) {
                int r = wc * 32 + ni * 16 + cl;
                int s = (kk * 4 + quad + r) & 7;
                b[ni] = *(const bf16x8*)&Bls[r * 64 + s * 8];
            }
#pragma unroll
            for (int mi = 0; mi < 4; ++mi)
#pragma unroll
                for (int ni = 0; ni < 2; ++ni)
                    acc[mi][ni] = __builtin_amdgcn_mfma_f32_16x16x32_bf16(
                        a[mi], b[ni], acc[mi][ni], 0, 0, 0);
        }
    }

    if (mode == 0) {
#pragma unroll
        for (int mi = 0; mi < 4; ++mi)
#pragma unroll
            for (int ni = 0; ni < 2; ++ni) {
                int col = colBase + wc * 32 + ni * 16 + cl;
                float bv = bias[col];
#pragma unroll
                for (int reg = 0; reg < 4; ++reg) {
                    int row = rowBase + wr * 64 + mi * 16 + quad * 4 + reg;
                    ((float*)O)[(size_t)row * 1024 + col] = acc[mi][ni][reg] + bv;
                }
            }
        return;
    }

    __syncthreads();
    short* Tls = ldsw;
    if (z == 2) {
        // vt (b,h,d,s): Tls[64][136]
#pragma unroll
        for (int mi = 0; mi < 4; ++mi)
#pragma unroll
            for (int ni = 0; ni < 2; ++ni) {
                int d = wc * 32 + ni * 16 + cl;
                float bv = bias[colBase + d];
                short4 pk;
                pk.x = f2bf(acc[mi][ni][0] + bv);
                pk.y = f2bf(acc[mi][ni][1] + bv);
                pk.z = f2bf(acc[mi][ni][2] + bv);
                pk.w = f2bf(acc[mi][ni][3] + bv);
                int sl = wr * 64 + mi * 16 + quad * 4;
                *(short4*)&Tls[d * 136 + sl] = pk;
            }
        __syncthreads();
        int d = t >> 2, s0 = (t & 3) * 32;
        int bb = rowBase >> 9, sBase = rowBase & 511, hh = colBase >> 6;
        short* dst = (short*)O + (((size_t)(bb * 16 + hh) * 64 + d) << 9) + sBase + s0;
#pragma unroll
        for (int j = 0; j < 4; ++j)
            *(bf16x8*)(dst + j * 8) = *(const bf16x8*)&Tls[d * 136 + s0 + j * 8];
    } else {
        // bhsd: Tls[128][72]
#pragma unroll
        for (int mi = 0; mi < 4; ++mi)
#pragma unroll
            for (int ni = 0; ni < 2; ++ni) {
                int d = wc * 32 + ni * 16 + cl;
                float bv = bias[colBase + d];
#pragma unroll
                for (int reg = 0; reg < 4; ++reg) {
                    int sl = wr * 64 + mi * 16 + quad * 4 + reg;
                    Tls[sl * 72 + d] = f2bf(acc[mi][ni][reg] + bv);
                }
            }
        __syncthreads();
        int sl = t >> 1, half = t & 1;
        int bb = rowBase >> 9, sBase = rowBase & 511, hh = colBase >> 6;
        short* dst = (short*)O + (((size_t)(bb * 16 + hh) * 512 + sBase + sl) << 6) + half * 32;
#pragma unroll
        for (int j = 0; j < 4; ++j)
            *(bf16x8*)(dst + j * 8) = *(const bf16x8*)&Tls[sl * 72 + half * 32 + j * 8];
    }
}

// ---------------- Attention: single-wave blocks + in-register software pipeline ----------------
// block = one 64-thread wave = (b,h, 16-query tile) x all 512 keys. Zero barriers.
// Pipeline: K(c+1), mask(c+1) prefetched into registers during chunk c;
// V(c) issued at top of chunk c (covered by score/exp/Pst phase).
// LDS wave-private: qwr f32[16][68] | bins f32[16][68] | Pst short[16][72] (binsBf aliases Pst).
#define AT_BINS 4352
#define AT_PST  8704
#define AT_TOT  11264

__global__ __launch_bounds__(64)
void attn_kernel(const short* __restrict__ qg, const short* __restrict__ kg,
                 const short* __restrict__ vtg, const int* __restrict__ mask,
                 const float* __restrict__ relk, const float* __restrict__ relv,
                 short* __restrict__ attn_b)
{
    __shared__ __align__(16) char pool[AT_TOT];
    float* qwr    = (float*)pool;
    float* bins   = (float*)(pool + AT_BINS);
    short* Pst    = (short*)(pool + AT_PST);
    short* binsBf = Pst;                       // aliases Pst after K-loop (Pst dead)

    const int lane = threadIdx.x;
    const int quad = lane >> 4, cl = lane & 15;
    const int bid = blockIdx.x;
    const int bh = bid & 63, qbk = bid >> 6;   // XCD-friendly: bh%8 fixes XCD
    const int b = bh >> 4, h = bh & 15, q0 = qbk * 16;

    const short* qbase = qg  + ((size_t)bh * 512 + q0) * 64;
    const short* kbase = kg  + (size_t)bh * 512 * 64;
    const short* vbase = vtg + (size_t)bh * 64 * 512;
    const int*   mb    = mask + (size_t)b * 512 * 512 + (size_t)q0 * 512;

    // zero bins
    for (int i = lane; i < 16 * 68; i += 64) bins[i] = 0.f;

    // Q A-fragments direct from global
    bf16x8 qa0 = *(const bf16x8*)(qbase + cl * 64 + quad * 8);
    bf16x8 qa1 = *(const bf16x8*)(qbase + cl * 64 + 32 + quad * 8);

    // qrel: all 4 r-tiles (wave-private)
#pragma unroll
    for (int rt = 0; rt < 4; ++rt) {
        const float* kp = relk + (size_t)(rt * 16 + cl) * 64 + quad * 8;
        bf16x8 rb0, rb1;
#pragma unroll
        for (int j = 0; j < 8; ++j) rb0[j] = f2bf(kp[j]);
#pragma unroll
        for (int j = 0; j < 8; ++j) rb1[j] = f2bf(kp[32 + j]);
        f32x4 qr = (f32x4){0.f, 0.f, 0.f, 0.f};
        qr = __builtin_amdgcn_mfma_f32_16x16x32_bf16(qa0, rb0, qr, 0, 0, 0);
        qr = __builtin_amdgcn_mfma_f32_16x16x32_bf16(qa1, rb1, qr, 0, 0, 0);
#pragma unroll
        for (int reg = 0; reg < 4; ++reg)
            qwr[(quad * 4 + reg) * 68 + rt * 16 + cl] = qr[reg];
    }

    // ---- pipelined K-loop: 8 chunks of 64 keys ----
    f32x4 oacc[4];
#pragma unroll
    for (int dt = 0; dt < 4; ++dt) oacc[dt] = (f32x4){0.f, 0.f, 0.f, 0.f};
    float lpart[4] = {0.f, 0.f, 0.f, 0.f};

    bf16x8 kbuf[2][8];
    int    ibuf[2][16];

    // prologue: chunk 0 K + mask
#pragma unroll
    for (int nt = 0; nt < 4; ++nt) {
        const short* kp = kbase + (size_t)(nt * 16 + cl) * 64 + quad * 8;
        kbuf[0][nt * 2]     = *(const bf16x8*)kp;
        kbuf[0][nt * 2 + 1] = *(const bf16x8*)(kp + 32);
    }
#pragma unroll
    for (int nt = 0; nt < 4; ++nt)
#pragma unroll
        for (int reg = 0; reg < 4; ++reg)
            ibuf[0][nt * 4 + reg] = mb[(quad * 4 + reg) * 512 + nt * 16 + cl];

#pragma unroll
    for (int c = 0; c < 8; ++c) {
        const int cur = c & 1, nxt = cur ^ 1;
        const int k0 = c * 64;

        // issue V(c) now — consumed after the score/exp/Pst phase
        bf16x8 vb[8];
#pragma unroll
        for (int dt = 0; dt < 4; ++dt) {
            const short* vp = vbase + (size_t)(dt * 16 + cl) * 512 + k0 + quad * 8;
            vb[dt * 2]     = *(const bf16x8*)vp;
            vb[dt * 2 + 1] = *(const bf16x8*)(vp + 32);
        }
        // prefetch K(c+1), mask(c+1)
        if (c < 7) {
            const int k1 = k0 + 64;
#pragma unroll
            for (int nt = 0; nt < 4; ++nt) {
                const short* kp = kbase + (size_t)(k1 + nt * 16 + cl) * 64 + quad * 8;
                kbuf[nxt][nt * 2]     = *(const bf16x8*)kp;
                kbuf[nxt][nt * 2 + 1] = *(const bf16x8*)(kp + 32);
            }
#pragma unroll
            for (int nt = 0; nt < 4; ++nt)
#pragma unroll
                for (int reg = 0; reg < 4; ++reg)
                    ibuf[nxt][nt * 4 + reg] = mb[(quad * 4 + reg) * 512 + k1 + nt * 16 + cl];
        }

        // scores from kbuf[cur] (already resident)
#pragma unroll
        for (int nt = 0; nt < 4; ++nt) {
            f32x4 s = (f32x4){0.f, 0.f, 0.f, 0.f};
            s = __builtin_amdgcn_mfma_f32_16x16x32_bf16(qa0, kbuf[cur][nt * 2],     s, 0, 0, 0);
            s = __builtin_amdgcn_mfma_f32_16x16x32_bf16(qa1, kbuf[cur][nt * 2 + 1], s, 0, 0, 0);
#pragma unroll
            for (int reg = 0; reg < 4; ++reg) {
                int q = quad * 4 + reg;
                int id = ibuf[cur][nt * 4 + reg];
                float sc = (s[reg] + 0.25f * qwr[q * 68 + id]) * 0.125f;
                float p = (id == 0) ? 0.f : __expf(sc);   // no-max softmax; masked -> 0
                lpart[reg] += p;
                atomicAdd(&bins[q * 68 + id], p);
                Pst[q * 72 + nt * 16 + cl] = f2bf(p);
            }
        }
        // P C-layout -> A-layout via wave-private LDS (in-wave RAW)
        bf16x8 pa0 = *(const bf16x8*)&Pst[cl * 72 + quad * 8];
        bf16x8 pa1 = *(const bf16x8*)&Pst[cl * 72 + 32 + quad * 8];
#pragma unroll
        for (int dt = 0; dt < 4; ++dt) {
            oacc[dt] = __builtin_amdgcn_mfma_f32_16x16x32_bf16(pa0, vb[dt * 2],     oacc[dt], 0, 0, 0);
            oacc[dt] = __builtin_amdgcn_mfma_f32_16x16x32_bf16(pa1, vb[dt * 2 + 1], oacc[dt], 0, 0, 0);
        }
    }

    // per-q softmax denominators, in-register (16-lane groups share q)
    float invq[4];
#pragma unroll
    for (int reg = 0; reg < 4; ++reg) {
        float l = lpart[reg];
#pragma unroll
        for (int m = 8; m >= 1; m >>= 1) l += __shfl_xor(l, m);
        invq[reg] = 1.0f / l;
    }

    // bins -> bf16 into binsBf (aliases Pst; in-wave ordering)
    {
        int q = lane >> 2, r0 = (lane & 3) * 16;
#pragma unroll
        for (int j = 0; j < 4; ++j) {
            float4 f = *(const float4*)&bins[q * 68 + r0 + j * 4];
            short4 o;
            o.x = f2bf(f.x); o.y = f2bf(f.y); o.z = f2bf(f.z); o.w = f2bf(f.w);
            *(short4*)&binsBf[q * 72 + r0 + j * 4] = o;
        }
    }

    // rel_out = bins @ relv, all 4 d-tiles; combine + normalize + store
    bf16x8 ba0 = *(const bf16x8*)&binsBf[cl * 72 + quad * 8];
    bf16x8 ba1 = *(const bf16x8*)&binsBf[cl * 72 + 32 + quad * 8];
#pragma unroll
    for (int dt = 0; dt < 4; ++dt) {
        const float* rp = relv + (size_t)(quad * 8) * 64 + dt * 16 + cl;
        bf16x8 rv0, rv1;
#pragma unroll
        for (int j = 0; j < 8; ++j) rv0[j] = f2bf(rp[j * 64]);
#pragma unroll
        for (int j = 0; j < 8; ++j) rv1[j] = f2bf(rp[2048 + j * 64]);
        f32x4 racc = (f32x4){0.f, 0.f, 0.f, 0.f};
        racc = __builtin_amdgcn_mfma_f32_16x16x32_bf16(ba0, rv0, racc, 0, 0, 0);
        racc = __builtin_amdgcn_mfma_f32_16x16x32_bf16(ba1, rv1, racc, 0, 0, 0);
#pragma unroll
        for (int reg = 0; reg < 4; ++reg) {
            int q = quad * 4 + reg;
            float val = (oacc[dt][reg] + 0.25f * racc[reg]) * invq[reg];
            attn_b[(size_t)(b * 512 + q0 + q) * 1024 + h * 64 + dt * 16 + cl] = f2bf(val);
        }
    }
}

extern "C" void kernel_launch(void* const* d_in, const int* in_sizes, int n_in,
                              void* d_out, int out_size, void* d_ws, size_t ws_size,
                              hipStream_t stream)
{
    const float* q_in = (const float*)d_in[0];
    const float* k_in = (const float*)d_in[1];
    const float* v_in = (const float*)d_in[2];
    const int*   mask = (const int*)d_in[3];
    const float* Wq   = (const float*)d_in[4];
    const float* bq   = (const float*)d_in[5];
    const float* Wk   = (const float*)d_in[6];
    const float* bk   = (const float*)d_in[7];
    const float* Wv   = (const float*)d_in[8];
    const float* bv   = (const float*)d_in[9];
    const float* Wo   = (const float*)d_in[10];
    const float* bo   = (const float*)d_in[11];
    const float* relk = (const float*)d_in[12];
    const float* relv = (const float*)d_in[13];

    char* ws = (char*)d_ws;
    short* qb     = (short*)(ws);                  // 4MB
    short* kb     = (short*)(ws + (4u  << 20));    // 4MB
    short* vt     = (short*)(ws + (8u  << 20));    // 4MB
    short* attn_b = (short*)(ws + (12u << 20));    // 4MB
    short* Xq     = (short*)(ws + (16u << 20));    // 4MB
    short* Xk     = (short*)(ws + (20u << 20));
    short* Xv     = (short*)(ws + (24u << 20));
    short* Wqb    = (short*)(ws + (28u << 20));    // 2MB
    short* Wkb    = (short*)(ws + (30u << 20));
    short* Wvb    = (short*)(ws + (32u << 20));
    short* Wob    = (short*)(ws + (34u << 20));

    cast_all<<<10240, 256, 0, stream>>>(q_in, k_in, v_in, Wq, Wk, Wv, Wo,
                                        Xq, Xk, Xv, Wqb, Wkb, Wvb, Wob);

    gemm12864<<<dim3(16, 16, 3), 256, 0, stream>>>(
        Xq, Xk, Xv, Wqb, Wkb, Wvb, bq, bk, bv, qb, kb, vt, 1);

    attn_kernel<<<dim3(2048), 64, 0, stream>>>(qb, kb, vt, mask, relk, relv, attn_b);

    gemm12864<<<dim3(16, 16, 1), 256, 0, stream>>>(
        attn_b, attn_b, attn_b, Wob, Wob, Wob, bo, bo, bo,
        (void*)d_out, (void*)d_out, (void*)d_out, 0);
}

// Round 11
// 243.056 us; speedup vs baseline: 1.0141x; 1.0051x over previous
//
#include <hip/hip_runtime.h>

// B=4, S=512, HID=1024, H=16, D=64, NREL=64
// ws: qb bf16(B,H,S,D) | kb bf16(B,H,S,D) | vt f16(B,H,D,S) | attn_b bf16(B*S,HID)
//     Xq,Xk,Xv bf16 | Wqb,Wkb,Wvb,Wob bf16 | qrelg f32(B*H*S,64) 8MB

typedef __attribute__((ext_vector_type(8))) short bf16x8 __attribute__((may_alias));
typedef __attribute__((ext_vector_type(4))) float f32x4;
typedef __attribute__((ext_vector_type(4))) _Float16 f16x4 __attribute__((may_alias));

__device__ __forceinline__ short f2bf(float x) {
    unsigned u = __float_as_uint(x);
    u += 0x7fff + ((u >> 16) & 1);          // RNE; finite inputs
    return (short)(u >> 16);
}
__device__ __forceinline__ short f2h(float x) {
    union { _Float16 h; short s; } u;
    u.h = (_Float16)x;
    return u.s;
}

__device__ __forceinline__ void async16(void* lds, const void* g) {
    __builtin_amdgcn_global_load_lds(
        (const __attribute__((address_space(1))) void*)g,
        (__attribute__((address_space(3))) void*)lds, 16, 0, 0);
}

// ---------- fused fp32 -> bf16 cast of 3 X (2M ea) + 4 W (1M ea) ----------
__global__ __launch_bounds__(256)
void cast_all(const float* __restrict__ x0, const float* __restrict__ x1, const float* __restrict__ x2,
              const float* __restrict__ w0, const float* __restrict__ w1,
              const float* __restrict__ w2, const float* __restrict__ w3,
              short* __restrict__ y0, short* __restrict__ y1, short* __restrict__ y2,
              short* __restrict__ u0, short* __restrict__ u1,
              short* __restrict__ u2, short* __restrict__ u3)
{
    size_t i = (size_t)blockIdx.x * 256 + threadIdx.x;
    const float* src; short* dst; size_t off;
    if (i < 3u*524288u) {
        int s = (int)(i / 524288u); off = i % 524288u;
        src = s == 0 ? x0 : (s == 1 ? x1 : x2);
        dst = s == 0 ? y0 : (s == 1 ? y1 : y2);
    } else {
        size_t j = i - 3u*524288u;
        int s = (int)(j / 262144u); off = j % 262144u;
        src = s == 0 ? w0 : (s == 1 ? w1 : (s == 2 ? w2 : w3));
        dst = s == 0 ? u0 : (s == 1 ? u1 : (s == 2 ? u2 : u3));
    }
    float4 f = ((const float4*)src)[off];
    short4 o; o.x = f2bf(f.x); o.y = f2bf(f.y); o.z = f2bf(f.z); o.w = f2bf(f.w);
    ((short4*)dst)[off] = o;
}

// ---------- bf16 MFMA GEMM, tile 128(M)x64(N), BK=64, dbuf: O = A @ B^T + bias ----------
// mode 0: O fp32 flat. mode 1: z<2 -> bf16 (b,h,s,d); z==2 -> **f16** (b,h,d,s).
__global__ __launch_bounds__(256)
void gemm12864(const short* __restrict__ A0, const short* __restrict__ A1, const short* __restrict__ A2,
               const short* __restrict__ B0, const short* __restrict__ B1, const short* __restrict__ B2,
               const float* __restrict__ c0, const float* __restrict__ c1, const float* __restrict__ c2,
               void* __restrict__ O0, void* __restrict__ O1, void* __restrict__ O2,
               int mode)
{
    __shared__ short ldsw[2 * 12288];   // [buf][A 128*64 | B 64*64]; epilogue reuses as Tls

    const int z = blockIdx.z;
    const short* A    = z == 0 ? A0 : (z == 1 ? A1 : A2);
    const short* Bm   = z == 0 ? B0 : (z == 1 ? B1 : B2);
    const float* bias = z == 0 ? c0 : (z == 1 ? c1 : c2);
    void*        O    = z == 0 ? O0 : (z == 1 ? O1 : O2);

    const int t = threadIdx.x;
    const int lane = t & 63, w = t >> 6;
    const int wr = w >> 1, wc = w & 1;
    const int quad = lane >> 4, cl = lane & 15;
    const int rowBase = blockIdx.y * 128;
    const int colBase = blockIdx.x * 64;
    const int gl = ((lane & 7) - (lane >> 3)) & 7;

    f32x4 acc[4][2];
#pragma unroll
    for (int i = 0; i < 4; ++i)
#pragma unroll
        for (int j = 0; j < 2; ++j) acc[i][j] = (f32x4){0.f, 0.f, 0.f, 0.f};

    const int rstage = w * 8 + (lane >> 3);
    const short* Ag = A  + (size_t)(rowBase + rstage) * 1024 + gl * 8;
    const short* Bg = Bm + (size_t)(colBase + rstage) * 1024 + gl * 8;

    {
        short* Als = ldsw;
        short* Bls = ldsw + 8192;
#pragma unroll
        for (int i = 0; i < 4; ++i)
            async16(&Als[(i * 32 + w * 8) * 64], Ag + (size_t)i * 32 * 1024);
#pragma unroll
        for (int i = 0; i < 2; ++i)
            async16(&Bls[(i * 32 + w * 8) * 64], Bg + (size_t)i * 32 * 1024);
    }

    for (int it = 0; it < 16; ++it) {
        const int cur = it & 1;
        __syncthreads();
        if (it < 15) {
            short* Als = ldsw + (cur ^ 1) * 12288;
            short* Bls = Als + 8192;
            const int k0 = (it + 1) * 64;
#pragma unroll
            for (int i = 0; i < 4; ++i)
                async16(&Als[(i * 32 + w * 8) * 64], Ag + (size_t)i * 32 * 1024 + k0);
#pragma unroll
            for (int i = 0; i < 2; ++i)
                async16(&Bls[(i * 32 + w * 8) * 64], Bg + (size_t)i * 32 * 1024 + k0);
        }
        const short* Als = ldsw + cur * 12288;
        const short* Bls = Als + 8192;
#pragma unroll
        for (int kk = 0; kk < 2; ++kk) {
            bf16x8 a[4], b[2];
#pragma unroll
            for (int mi = 0; mi < 4; ++mi) {
                int r = wr * 64 + mi * 16 + cl;
                int s = (kk * 4 + quad + r) & 7;
                a[mi] = *(const bf16x8*)&Als[r * 64 + s * 8];
            }
#pragma unroll
            for (int ni = 0; ni < 2; ++ni) {
                int r = wc * 32 + ni * 16 + cl;
                int s = (kk * 4 + quad + r) & 7;
                b[ni] = *(const bf16x8*)&Bls[r * 64 + s * 8];
            }
#pragma unroll
            for (int mi = 0; mi < 4; ++mi)
#pragma unroll
                for (int ni = 0; ni < 2; ++ni)
                    acc[mi][ni] = __builtin_amdgcn_mfma_f32_16x16x32_bf16(
                        a[mi], b[ni], acc[mi][ni], 0, 0, 0);
        }
    }

    if (mode == 0) {
#pragma unroll
        for (int mi = 0; mi < 4; ++mi)
#pragma unroll
            for (int ni = 0; ni < 2; ++ni) {
                int col = colBase + wc * 32 + ni * 16 + cl;
                float bv = bias[col];
#pragma unroll
                for (int reg = 0; reg < 4; ++reg) {
                    int row = rowBase + wr * 64 + mi * 16 + quad * 4 + reg;
                    ((float*)O)[(size_t)row * 1024 + col] = acc[mi][ni][reg] + bv;
                }
            }
        return;
    }

    __syncthreads();
    short* Tls = ldsw;
    if (z == 2) {
        // vt (b,h,d,s) in f16: Tls[64][136]
#pragma unroll
        for (int mi = 0; mi < 4; ++mi)
#pragma unroll
            for (int ni = 0; ni < 2; ++ni) {
                int d = wc * 32 + ni * 16 + cl;
                float bv = bias[colBase + d];
                short4 pk;
                pk.x = f2h(acc[mi][ni][0] + bv);
                pk.y = f2h(acc[mi][ni][1] + bv);
                pk.z = f2h(acc[mi][ni][2] + bv);
                pk.w = f2h(acc[mi][ni][3] + bv);
                int sl = wr * 64 + mi * 16 + quad * 4;
                *(short4*)&Tls[d * 136 + sl] = pk;
            }
        __syncthreads();
        int d = t >> 2, s0 = (t & 3) * 32;
        int bb = rowBase >> 9, sBase = rowBase & 511, hh = colBase >> 6;
        short* dst = (short*)O + (((size_t)(bb * 16 + hh) * 64 + d) << 9) + sBase + s0;
#pragma unroll
        for (int j = 0; j < 4; ++j)
            *(bf16x8*)(dst + j * 8) = *(const bf16x8*)&Tls[d * 136 + s0 + j * 8];
    } else {
        // bhsd bf16: Tls[128][72]
#pragma unroll
        for (int mi = 0; mi < 4; ++mi)
#pragma unroll
            for (int ni = 0; ni < 2; ++ni) {
                int d = wc * 32 + ni * 16 + cl;
                float bv = bias[colBase + d];
#pragma unroll
                for (int reg = 0; reg < 4; ++reg) {
                    int sl = wr * 64 + mi * 16 + quad * 4 + reg;
                    Tls[sl * 72 + d] = f2bf(acc[mi][ni][reg] + bv);
                }
            }
        __syncthreads();
        int sl = t >> 1, half = t & 1;
        int bb = rowBase >> 9, sBase = rowBase & 511, hh = colBase >> 6;
        short* dst = (short*)O + (((size_t)(bb * 16 + hh) * 512 + sBase + sl) << 6) + half * 32;
#pragma unroll
        for (int j = 0; j < 4; ++j)
            *(bf16x8*)(dst + j * 8) = *(const bf16x8*)&Tls[sl * 72 + half * 32 + j * 8];
    }
}

// ---------- qrel precompute: qrelg[bh*512+q][r] = q . relk[r] ----------
__global__ __launch_bounds__(64)
void qrel_kernel(const short* __restrict__ qg, const float* __restrict__ relk,
                 float* __restrict__ qrelg)
{
    const int lane = threadIdx.x;
    const int quad = lane >> 4, cl = lane & 15;
    const int bid = blockIdx.x;
    const int bh = bid & 63, qbk = bid >> 6;
    const int q0 = qbk * 16;

    const short* qbase = qg + ((size_t)bh * 512 + q0) * 64;
    float* out = qrelg + ((size_t)bh * 512 + q0) * 64;

    bf16x8 qa0 = *(const bf16x8*)(qbase + cl * 64 + quad * 8);
    bf16x8 qa1 = *(const bf16x8*)(qbase + cl * 64 + 32 + quad * 8);

#pragma unroll
    for (int rt = 0; rt < 4; ++rt) {
        const float* kp = relk + (size_t)(rt * 16 + cl) * 64 + quad * 8;
        bf16x8 rb0, rb1;
#pragma unroll
        for (int j = 0; j < 8; ++j) rb0[j] = f2bf(kp[j]);
#pragma unroll
        for (int j = 0; j < 8; ++j) rb1[j] = f2bf(kp[32 + j]);
        f32x4 qr = (f32x4){0.f, 0.f, 0.f, 0.f};
        qr = __builtin_amdgcn_mfma_f32_16x16x32_bf16(qa0, rb0, qr, 0, 0, 0);
        qr = __builtin_amdgcn_mfma_f32_16x16x32_bf16(qa1, rb1, qr, 0, 0, 0);
#pragma unroll
        for (int reg = 0; reg < 4; ++reg)
            out[(size_t)(quad * 4 + reg) * 64 + rt * 16 + cl] = qr[reg];
    }
}

// ---------------- Attention: ds-minimal (bins atomics only) ----------------
// block = one wave = (b,h, 16-query tile) x 512 keys. Zero barriers.
// P transposed C->A via identity MFMA (no LDS); PV = K=16 f16 MFMAs; V stored f16.
// qrel gathered from GLOBAL (precomputed); LDS = bins 4.3KB + binsBf 2.3KB.
__global__ __launch_bounds__(64)
void attn_kernel(const short* __restrict__ qg, const short* __restrict__ kg,
                 const _Float16* __restrict__ vtg, const int* __restrict__ mask,
                 const float* __restrict__ qrelg, const float* __restrict__ relv,
                 short* __restrict__ attn_b)
{
    __shared__ __align__(16) float bins[16 * 68];
    __shared__ __align__(16) short binsBf[16 * 72];

    const int lane = threadIdx.x;
    const int quad = lane >> 4, cl = lane & 15;
    const int bid = blockIdx.x;
    const int bh = bid & 63, qbk = bid >> 6;   // XCD-friendly: bh%8 fixes XCD
    const int b = bh >> 4, h = bh & 15, q0 = qbk * 16;

    const short*    qbase = qg  + ((size_t)bh * 512 + q0) * 64;
    const short*    kbase = kg  + (size_t)bh * 512 * 64;
    const _Float16* vbase = vtg + (size_t)bh * 64 * 512;
    const int*      mb    = mask + (size_t)b * 512 * 512 + (size_t)q0 * 512;
    const float*    qrb   = qrelg + ((size_t)bh * 512 + q0) * 64;

    for (int i = lane; i < 16 * 68; i += 64) bins[i] = 0.f;

    bf16x8 qa0 = *(const bf16x8*)(qbase + cl * 64 + quad * 8);
    bf16x8 qa1 = *(const bf16x8*)(qbase + cl * 64 + 32 + quad * 8);

    // identity B-operand for the transpose MFMA (B[k][n] = delta(k,n))
    f16x4 idB;
#pragma unroll
    for (int j = 0; j < 4; ++j) idB[j] = (quad * 4 + j == cl) ? (_Float16)1.0f : (_Float16)0.0f;

    f32x4 oacc[4];
#pragma unroll
    for (int dt = 0; dt < 4; ++dt) oacc[dt] = (f32x4){0.f, 0.f, 0.f, 0.f};
    float lpart[4] = {0.f, 0.f, 0.f, 0.f};

    for (int c = 0; c < 8; ++c) {
        const int k0 = c * 64;
        // all V fragments for this chunk (16 x 8B, independent, issue early)
        f16x4 vb[4][4];
#pragma unroll
        for (int nt = 0; nt < 4; ++nt)
#pragma unroll
            for (int dt = 0; dt < 4; ++dt)
                vb[nt][dt] = *(const f16x4*)(vbase + (size_t)(dt * 16 + cl) * 512
                                             + k0 + nt * 16 + quad * 4);

#pragma unroll
        for (int nt = 0; nt < 4; ++nt) {
            const int kidx = k0 + nt * 16 + cl;
            const short* kp = kbase + (size_t)kidx * 64 + quad * 8;
            bf16x8 kb0 = *(const bf16x8*)kp;
            bf16x8 kb1 = *(const bf16x8*)(kp + 32);
            f32x4 s = (f32x4){0.f, 0.f, 0.f, 0.f};
            s = __builtin_amdgcn_mfma_f32_16x16x32_bf16(qa0, kb0, s, 0, 0, 0);
            s = __builtin_amdgcn_mfma_f32_16x16x32_bf16(qa1, kb1, s, 0, 0, 0);

            f16x4 pA;
#pragma unroll
            for (int reg = 0; reg < 4; ++reg) {
                int q = quad * 4 + reg;
                int id = mb[q * 512 + kidx];                 // global scalar (TA)
                float sc = (s[reg] + 0.25f * qrb[q * 64 + id]) * 0.125f;  // global gather (TA)
                float p = (id == 0) ? 0.f : __expf(sc);      // no-max softmax
                lpart[reg] += p;
                atomicAdd(&bins[q * 68 + id], p);            // the only ds op left
                pA[reg] = (_Float16)p;
            }
            // C->A transpose via MFMA: D holds p[q=cl][k=quad*4+reg]
            f32x4 tD = __builtin_amdgcn_mfma_f32_16x16x16f16(pA, idB,
                         (f32x4){0.f, 0.f, 0.f, 0.f}, 0, 0, 0);
            f16x4 paT;
#pragma unroll
            for (int j = 0; j < 4; ++j) paT[j] = (_Float16)tD[j];
#pragma unroll
            for (int dt = 0; dt < 4; ++dt)
                oacc[dt] = __builtin_amdgcn_mfma_f32_16x16x16f16(paT, vb[nt][dt],
                                                                 oacc[dt], 0, 0, 0);
        }
    }

    // per-q softmax denominators (16-lane groups share q)
    float invq[4];
#pragma unroll
    for (int reg = 0; reg < 4; ++reg) {
        float l = lpart[reg];
#pragma unroll
        for (int m = 8; m >= 1; m >>= 1) l += __shfl_xor(l, m);
        invq[reg] = 1.0f / l;
    }

    // bins -> bf16
    {
        int q = lane >> 2, r0 = (lane & 3) * 16;
#pragma unroll
        for (int j = 0; j < 4; ++j) {
            float4 f = *(const float4*)&bins[q * 68 + r0 + j * 4];
            short4 o;
            o.x = f2bf(f.x); o.y = f2bf(f.y); o.z = f2bf(f.z); o.w = f2bf(f.w);
            *(short4*)&binsBf[q * 72 + r0 + j * 4] = o;
        }
    }

    // rel_out = bins @ relv (K=32 bf16), combine + normalize + store
    bf16x8 ba0 = *(const bf16x8*)&binsBf[cl * 72 + quad * 8];
    bf16x8 ba1 = *(const bf16x8*)&binsBf[cl * 72 + 32 + quad * 8];
#pragma unroll
    for (int dt = 0; dt < 4; ++dt) {
        const float* rp = relv + (size_t)(quad * 8) * 64 + dt * 16 + cl;
        bf16x8 rv0, rv1;
#pragma unroll
        for (int j = 0; j < 8; ++j) rv0[j] = f2bf(rp[j * 64]);
#pragma unroll
        for (int j = 0; j < 8; ++j) rv1[j] = f2bf(rp[2048 + j * 64]);
        f32x4 racc = (f32x4){0.f, 0.f, 0.f, 0.f};
        racc = __builtin_amdgcn_mfma_f32_16x16x32_bf16(ba0, rv0, racc, 0, 0, 0);
        racc = __builtin_amdgcn_mfma_f32_16x16x32_bf16(ba1, rv1, racc, 0, 0, 0);
#pragma unroll
        for (int reg = 0; reg < 4; ++reg) {
            int q = quad * 4 + reg;
            float val = (oacc[dt][reg] + 0.25f * racc[reg]) * invq[reg];
            attn_b[(size_t)(b * 512 + q0 + q) * 1024 + h * 64 + dt * 16 + cl] = f2bf(val);
        }
    }
}

extern "C" void kernel_launch(void* const* d_in, const int* in_sizes, int n_in,
                              void* d_out, int out_size, void* d_ws, size_t ws_size,
                              hipStream_t stream)
{
    const float* q_in = (const float*)d_in[0];
    const float* k_in = (const float*)d_in[1];
    const float* v_in = (const float*)d_in[2];
    const int*   mask = (const int*)d_in[3];
    const float* Wq   = (const float*)d_in[4];
    const float* bq   = (const float*)d_in[5];
    const float* Wk   = (const float*)d_in[6];
    const float* bk   = (const float*)d_in[7];
    const float* Wv   = (const float*)d_in[8];
    const float* bv   = (const float*)d_in[9];
    const float* Wo   = (const float*)d_in[10];
    const float* bo   = (const float*)d_in[11];
    const float* relk = (const float*)d_in[12];
    const float* relv = (const float*)d_in[13];

    char* ws = (char*)d_ws;
    short*     qb     = (short*)(ws);                  // 4MB
    short*     kb     = (short*)(ws + (4u  << 20));    // 4MB
    _Float16*  vt     = (_Float16*)(ws + (8u << 20));  // 4MB (f16)
    short*     attn_b = (short*)(ws + (12u << 20));    // 4MB
    short*     Xq     = (short*)(ws + (16u << 20));    // 4MB
    short*     Xk     = (short*)(ws + (20u << 20));
    short*     Xv     = (short*)(ws + (24u << 20));
    short*     Wqb    = (short*)(ws + (28u << 20));    // 2MB
    short*     Wkb    = (short*)(ws + (30u << 20));
    short*     Wvb    = (short*)(ws + (32u << 20));
    short*     Wob    = (short*)(ws + (34u << 20));
    float*     qrelg  = (float*)(ws + (36u << 20));    // 8MB

    cast_all<<<10240, 256, 0, stream>>>(q_in, k_in, v_in, Wq, Wk, Wv, Wo,
                                        Xq, Xk, Xv, Wqb, Wkb, Wvb, Wob);

    gemm12864<<<dim3(16, 16, 3), 256, 0, stream>>>(
        Xq, Xk, Xv, Wqb, Wkb, Wvb, bq, bk, bv, qb, kb, vt, 1);

    qrel_kernel<<<dim3(2048), 64, 0, stream>>>(qb, relk, qrelg);

    attn_kernel<<<dim3(2048), 64, 0, stream>>>(qb, kb, vt, mask, qrelg, relv, attn_b);

    gemm12864<<<dim3(16, 16, 1), 256, 0, stream>>>(
        attn_b, attn_b, attn_b, Wob, Wob, Wob, bo, bo, bo,
        (void*)d_out, (void*)d_out, (void*)d_out, 0);
}